// Round 8
// baseline (455.217 us; speedup 1.0000x reference)
//
#include <hip/hip_runtime.h>
#include <float.h>

#define T_TOTAL 32768
#define KC      8192
#define DIM     256

#define LOSS_IDX  ((size_t)T_TOTAL * DIM)      // 8388608
#define USAGE_IDX (LOSS_IDX + 1)

typedef short s16x8 __attribute__((ext_vector_type(8)));
typedef float f32x4 __attribute__((ext_vector_type(4)));

// ws layout (bytes):
#define WS_W2    0                 // f32[8192]
#define WS_FLAGS 32768             // i32[8192]
#define WS_CBF   65536             // u16[8192*256] = 4 MB

__device__ __forceinline__ unsigned short f2bf(float f) {
    unsigned int u = __float_as_uint(f);
    u += 0x7FFFu + ((u >> 16) & 1u);   // RTNE
    return (unsigned short)(u >> 16);
}

// ---------------------------------------------------------------------------
// prep: cb->bf16 + exact fp32 w2; flags zero (blocks 0..31); global argmin
// keys (in out's z_q slots, 8 B/token) init ~0 (blocks 0..127); scalars (blk 0)
__global__ __launch_bounds__(256) void vq_prep(const float* __restrict__ cb,
                                               unsigned short* __restrict__ cbb,
                                               float* __restrict__ w2,
                                               int* __restrict__ flags,
                                               float* __restrict__ out) {
    const int blk = blockIdx.x, tid = threadIdx.x;
    size_t i = (size_t)blk * 2048 + (size_t)tid * 8;
    float4 a = *(const float4*)(cb + i);
    float4 b = *(const float4*)(cb + i + 4);
    uint4 o;
    o.x = (unsigned)f2bf(a.x) | ((unsigned)f2bf(a.y) << 16);
    o.y = (unsigned)f2bf(a.z) | ((unsigned)f2bf(a.w) << 16);
    o.z = (unsigned)f2bf(b.x) | ((unsigned)f2bf(b.y) << 16);
    o.w = (unsigned)f2bf(b.z) | ((unsigned)f2bf(b.w) << 16);
    *(uint4*)(cbb + i) = o;
    float s = a.x * a.x + a.y * a.y + a.z * a.z + a.w * a.w
            + b.x * b.x + b.y * b.y + b.z * b.z + b.w * b.w;
    #pragma unroll
    for (int m = 1; m <= 16; m <<= 1) s += __shfl_xor(s, m);
    if ((tid & 31) == 0) w2[blk * 8 + (tid >> 5)] = s;
    if (blk < 32) flags[blk * 256 + tid] = 0;
    if (blk < 128) {
        int t = blk * 256 + tid;   // 32768 tokens: key slot at out[t*256..+1]
        *(unsigned long long*)(out + ((size_t)t << 8)) = ~0ULL;
    }
    if (blk == 0 && tid == 0) { out[LOSS_IDX] = 0.0f; out[USAGE_IDX] = 0.0f; }
}

// ---------------------------------------------------------------------------
// main: block = 512 tokens x ONE QUARTER of the codebook (2048 codes).
// grid 256 = 64 token-groups x 4 quarters; blockIdx%8 keeps one quarter per
// XCD (1 MB, L2-resident). 8 waves; wave w owns tokens [t0+w*64, +64).
//
// R7: NO LDS STAGING. R6 (156us, MfmaUtil 40) showed the residual cost is
// the staging round-trip itself: per CU 8 MB glds-write + 8 MB ds_read of
// LDS-port traffic (~60us) that L1-dedup cannot remove, stacked on the MFMA
// floor (66us) with only 2 waves/SIMD to overlap them. But the MFMA
// B-fragment is DIRECTLY gather-loadable: lane needs 16 B at
// row(l15)*512B + quad*16B (+ kw*128B + kk*64B), and lanes {l15,l15+16,
// l15+32,l15+48} form full 64 B segments -> a global_load_dwordx4 gather
// has 100% transaction efficiency, the same L1 segment count as staging
// alone, and ZERO LDS traffic. All 8 waves read identical addresses in
// natural lockstep (no barriers) -> L1 dedups the L2 traffic as in R6.
// Prefetch: window n+1's 4 loads issue before window n's 16 MFMAs (~310cyc
// issue) -> covers L2-hit latency (~225cyc). The compiler inserts exact
// counted vmcnt waits for the register deps (G7/m97) -- no manual waitcnt.
// LDS holds only this quarter's w2 (8 KB). Register pressure == R6
// (regB[2][4], af[4][8]) -> 2 waves/SIMD preserved.
__global__ __launch_bounds__(512, 2) void vq_main(const unsigned short* __restrict__ cbb,
                                                  const float* __restrict__ w2g,
                                                  const float* __restrict__ z_e,
                                                  float* __restrict__ out) {
    __shared__ float w2s[2048];   // this quarter's w2, 8 KB

    const int tid  = threadIdx.x;
    const int lane = tid & 63;
    const int w    = tid >> 6;        // 0..7 = token octile
    const int quad = lane >> 4;
    const int l15  = lane & 15;
    const int tb   = blockIdx.x >> 2; // token group (512 tokens)
    const int cq   = blockIdx.x & 3;  // code quarter
    const int t0   = tb * 512;
    const int cbase = cq * 2048;

    // B gather bases: frag (kk,j) of chunk c, k-window kw (elements):
    //   pb{j} + c*8192 + kw*64 + kk*32
    //   == (cbase + c*32 + j*16 + l15)*DIM + kw*64 + kk*32 + quad*8
    // kw*64+kk*32 <= 224 elems = 448 B -> folds into the 13-bit load offset.
    const unsigned short* pb0 = cbb + (size_t)(cbase + l15) * DIM + quad * 8;
    const unsigned short* pb1 = pb0 + 16 * DIM;

    // prologue: quarter w2 -> LDS (512 float4 = 8 KB), build A from fp32 z_e
    ((float4*)w2s)[tid] = ((const float4*)(w2g + cbase))[tid];
    s16x8 af[4][8];
    #pragma unroll
    for (int i = 0; i < 4; ++i) {
        #pragma unroll
        for (int ks = 0; ks < 8; ++ks) {
            const float* p = z_e + (size_t)(t0 + w * 64 + i * 16 + l15) * DIM + ks * 32 + quad * 8;
            float4 a = *(const float4*)p;
            float4 b = *(const float4*)(p + 4);
            s16x8 v;
            v[0] = (short)f2bf(a.x); v[1] = (short)f2bf(a.y);
            v[2] = (short)f2bf(a.z); v[3] = (short)f2bf(a.w);
            v[4] = (short)f2bf(b.x); v[5] = (short)f2bf(b.y);
            v[6] = (short)f2bf(b.z); v[7] = (short)f2bf(b.w);
            af[i][ks] = v;
        }
    }

    float best[4][4];
    int   bidx[4][4];
    #pragma unroll
    for (int i = 0; i < 4; ++i)
        #pragma unroll
        for (int r = 0; r < 4; ++r) { best[i][r] = FLT_MAX; bidx[i][r] = 0x7FFFFFFF; }

    __syncthreads();   // w2s published (also drains prologue loads)

    // prime: window 0 -> regB[0]
    s16x8 regB[2][4];
    regB[0][0] = *(const s16x8*)(pb0);
    regB[0][1] = *(const s16x8*)(pb1);
    regB[0][2] = *(const s16x8*)(pb0 + 32);
    regB[0][3] = *(const s16x8*)(pb1 + 32);

    for (int c = 0; c < 64; ++c) {
        f32x4 acc[4][2];
        #pragma unroll
        for (int i = 0; i < 4; ++i)
            #pragma unroll
            for (int j = 0; j < 2; ++j) acc[i][j] = (f32x4){0.f, 0.f, 0.f, 0.f};

        #pragma unroll
        for (int kw = 0; kw < 4; ++kw) {
            // issue window n+1 (n = c*4+kw) -> regB[(kw+1)&1]; dummy wrap at end
            const int c2  = (kw < 3) ? c : ((c + 1) & 63);
            const int kw2 = (kw + 1) & 3;
            const unsigned short* q0 = pb0 + (size_t)c2 * 8192;
            const unsigned short* q1 = pb1 + (size_t)c2 * 8192;
            s16x8 nf0 = *(const s16x8*)(q0 + kw2 * 64);
            s16x8 nf1 = *(const s16x8*)(q1 + kw2 * 64);
            s16x8 nf2 = *(const s16x8*)(q0 + kw2 * 64 + 32);
            s16x8 nf3 = *(const s16x8*)(q1 + kw2 * 64 + 32);
            // 16 MFMAs on window n (loads issued one phase ago; compiler
            // emits the counted vmcnt for the regB dep)
            const s16x8* cur = regB[kw & 1];
            __builtin_amdgcn_s_setprio(1);
            #pragma unroll
            for (int kk = 0; kk < 2; ++kk)
                #pragma unroll
                for (int i = 0; i < 4; ++i)
                    #pragma unroll
                    for (int j = 0; j < 2; ++j)
                        acc[i][j] = __builtin_amdgcn_mfma_f32_16x16x32_bf16(af[i][kw * 2 + kk], cur[kk * 2 + j], acc[i][j], 0, 0, 0);
            __builtin_amdgcn_s_setprio(0);
            regB[(kw + 1) & 1][0] = nf0;
            regB[(kw + 1) & 1][1] = nf1;
            regB[(kw + 1) & 1][2] = nf2;
            regB[(kw + 1) & 1][3] = nf3;
        }

        // fold chunk c into running argmin: score = w2[col] - 2*dot
        #pragma unroll
        for (int j = 0; j < 2; ++j) {
            int col = cbase + c * 32 + j * 16 + l15;
            float w2v = w2s[c * 32 + j * 16 + l15];
            #pragma unroll
            for (int i = 0; i < 4; ++i)
                #pragma unroll
                for (int r = 0; r < 4; ++r) {
                    float s = fmaf(-2.0f, acc[i][j][r], w2v);
                    if (s < best[i][r]) { best[i][r] = s; bidx[i][r] = col; }  // ascending col: < keeps lowest
                }
        }
    }

    // cross-lane argmin over the 16 cols held per token row, then global
    // atomicMin merge across the 4 code-quarter blocks (monotonic u64 key)
    #pragma unroll
    for (int i = 0; i < 4; ++i)
        #pragma unroll
        for (int r = 0; r < 4; ++r) {
            float b = best[i][r]; int ix = bidx[i][r];
            #pragma unroll
            for (int m = 1; m < 16; m <<= 1) {
                float ob = __shfl_xor(b, m);
                int   oi = __shfl_xor(ix, m);
                if (ob < b || (ob == b && oi < ix)) { b = ob; ix = oi; }
            }
            if (l15 == 0) {
                unsigned int fb = __float_as_uint(b);
                fb = (fb & 0x80000000u) ? ~fb : (fb | 0x80000000u);   // monotonic key
                unsigned long long key = ((unsigned long long)fb << 32) | (unsigned int)ix;
                int tok = t0 + w * 64 + i * 16 + quad * 4 + r;
                atomicMin((unsigned long long*)(out + ((size_t)tok << 8)), key);
            }
        }
}

// ---------------------------------------------------------------------------
// gather: read final argmin keys from out's z_q slots, gather codebook rows
// (overwriting the keys), fused loss + usage (first-setter counting).
// block = 64 tokens, grid 512.
__global__ __launch_bounds__(256) void vq_gather(const float* __restrict__ cb,
                                                 const float* __restrict__ z_e,
                                                 float* __restrict__ out,
                                                 int* __restrict__ flags) {
    __shared__ float wls[4];
    const int tid  = threadIdx.x;
    const int lane = tid & 63;
    const int w    = tid >> 6;        // 0..3
    const int t0   = blockIdx.x * 64;

    float lsum = 0.0f;
    for (int t = w * 16; t < w * 16 + 16; ++t) {
        int tok = t0 + t;
        // all 64 lanes read the same 8 B key (broadcast), THEN overwrite
        unsigned long long key = *(const unsigned long long*)(out + ((size_t)tok << 8));
        int k = (int)(unsigned int)(key & 0xFFFFFFFFull);
        if (lane == 0) {
            if (atomicExch(&flags[k], 1) == 0)
                atomicAdd(out + USAGE_IDX, 1.0f / (float)KC);   // 2^-13: exact
        }
        float4 cv = *(const float4*)(cb + (size_t)k * DIM + lane * 4);
        float4 zv = *(const float4*)(z_e + (size_t)tok * DIM + lane * 4);
        float dx = zv.x - cv.x, dy = zv.y - cv.y, dz = zv.z - cv.z, dw = zv.w - cv.w;
        lsum += dx * dx + dy * dy + dz * dz + dw * dw;
        *(float4*)(out + ((size_t)tok << 8) + lane * 4) = cv;
    }
    #pragma unroll
    for (int m = 32; m >= 1; m >>= 1) lsum += __shfl_xor(lsum, m);
    if (lane == 0) wls[w] = lsum;
    __syncthreads();
    if (tid == 0) {
        float bsum = wls[0] + wls[1] + wls[2] + wls[3];
        // loss = codebook + 0.25*commitment = 1.25 * mean(diff^2)
        atomicAdd(out + LOSS_IDX, bsum * (1.25f / (float)LOSS_IDX));
    }
}

// ---------------------------------------------------------------------------
extern "C" void kernel_launch(void* const* d_in, const int* in_sizes, int n_in,
                              void* d_out, int out_size, void* d_ws, size_t ws_size,
                              hipStream_t stream) {
    (void)in_sizes; (void)n_in; (void)out_size; (void)ws_size;
    const float* z_e = (const float*)d_in[0];
    const float* cb  = (const float*)d_in[1];
    float* out = (float*)d_out;

    char* ws = (char*)d_ws;
    float* w2    = (float*)(ws + WS_W2);
    int*   flags = (int*)(ws + WS_FLAGS);
    unsigned short* cbb = (unsigned short*)(ws + WS_CBF);

    vq_prep<<<KC / 8, 256, 0, stream>>>(cb, cbb, w2, flags, out);
    vq_main<<<256, 512, 0, stream>>>(cbb, w2, z_e, out);
    vq_gather<<<T_TOTAL / 64, 256, 0, stream>>>(cb, z_e, out, flags);
}

// Round 9
// 255.639 us; speedup vs baseline: 1.7807x; 1.7807x over previous
//
#include <hip/hip_runtime.h>
#include <float.h>

#define T_TOTAL 32768
#define KC      8192
#define DIM     256

#define LOSS_IDX  ((size_t)T_TOTAL * DIM)      // 8388608
#define USAGE_IDX (LOSS_IDX + 1)

typedef short s16x8 __attribute__((ext_vector_type(8)));
typedef float f32x4 __attribute__((ext_vector_type(4)));

// ws layout (bytes):
#define WS_W2    0                 // f32[8192]
#define WS_FLAGS 32768             // i32[8192]
#define WS_CBF   65536             // u16[8192*256] = 4 MB

__device__ __forceinline__ unsigned short f2bf(float f) {
    unsigned int u = __float_as_uint(f);
    u += 0x7FFFu + ((u >> 16) & 1u);   // RTNE
    return (unsigned short)(u >> 16);
}

// ---------------------------------------------------------------------------
// prep: cb->bf16 + exact fp32 w2; flags zero (blocks 0..31); global argmin
// keys (in out's z_q slots, 8 B/token) init ~0 (blocks 0..127); scalars (blk 0)
__global__ __launch_bounds__(256) void vq_prep(const float* __restrict__ cb,
                                               unsigned short* __restrict__ cbb,
                                               float* __restrict__ w2,
                                               int* __restrict__ flags,
                                               float* __restrict__ out) {
    const int blk = blockIdx.x, tid = threadIdx.x;
    size_t i = (size_t)blk * 2048 + (size_t)tid * 8;
    float4 a = *(const float4*)(cb + i);
    float4 b = *(const float4*)(cb + i + 4);
    uint4 o;
    o.x = (unsigned)f2bf(a.x) | ((unsigned)f2bf(a.y) << 16);
    o.y = (unsigned)f2bf(a.z) | ((unsigned)f2bf(a.w) << 16);
    o.z = (unsigned)f2bf(b.x) | ((unsigned)f2bf(b.y) << 16);
    o.w = (unsigned)f2bf(b.z) | ((unsigned)f2bf(b.w) << 16);
    *(uint4*)(cbb + i) = o;
    float s = a.x * a.x + a.y * a.y + a.z * a.z + a.w * a.w
            + b.x * b.x + b.y * b.y + b.z * b.z + b.w * b.w;
    #pragma unroll
    for (int m = 1; m <= 16; m <<= 1) s += __shfl_xor(s, m);
    if ((tid & 31) == 0) w2[blk * 8 + (tid >> 5)] = s;
    if (blk < 32) flags[blk * 256 + tid] = 0;
    if (blk < 128) {
        int t = blk * 256 + tid;   // 32768 tokens: key slot at out[t*256..+1]
        *(unsigned long long*)(out + ((size_t)t << 8)) = ~0ULL;
    }
    if (blk == 0 && tid == 0) { out[LOSS_IDX] = 0.0f; out[USAGE_IDX] = 0.0f; }
}

// ---------------------------------------------------------------------------
// main: block = 512 tokens x ONE QUARTER of the codebook (2048 codes).
// grid 256 = 64 token-groups x 4 quarters (quarter per XCD-pair, L2-resident).
// 8 waves; wave w owns tokens [t0+w*64, +64), A in 128 regs.
//
// R8: SHARED single-copy staging. R6 (156us) was LDS-port-bound: 8 waves
// kept 8 private copies of IDENTICAL window data (64 LDS insts/CU-phase ~
// 640 cyc > 621 cyc MFMA). R7's register gather hit the VMEM-return/MSHR
// wall (282us). Here ONE wave stages each window into ONE shared 4-deep
// buffer cs[4][2048] (16 KB) via glds DMA; all 8 read it. T3/T4 protocol
// (counted-per-wave vmcnt + RAW s_barrier, never a drain-all in the loop):
//   phase p (= c*4+kw):
//     stager  w==(p+4)&7 : STAGE window p+4 -> buf[p&3]  (4 glds, 4 KB)
//     drainer w==(p+2)&7 : vmcnt(0)  [its batch for window p+2, issued at
//                          p-2, ~1200cyc old -> near-free; publishes p+2
//                          at this phase's barrier]
//     all: READFRAGS(window p+1 from buf[(p+1)&3])   [p+1 published at
//          barrier p-1: stager drained it at p-1]
//     all: 16 MFMAs on regB[p&1] (window p, read one phase ago)
//     all: lgkmcnt(0); s_barrier   [my reads of p+1 retired -> buf[(p+1)&3]
//          restageable at p+1; WAR ledger closed]
// LDS insts/CU-phase: 32 reads + 4 writes = 36 (was 64) -> under the MFMA
// budget. L2 staging traffic 8x down. Buffers+w2 = 24 KB LDS total.
__global__ __launch_bounds__(512, 2) void vq_main(const unsigned short* __restrict__ cbb,
                                                  const float* __restrict__ w2g,
                                                  const float* __restrict__ z_e,
                                                  float* __restrict__ out) {
    __shared__ unsigned short cs[4 * 2048];   // shared 4-deep window ring, 16 KB
    __shared__ float w2s[2048];               // this quarter's w2, 8 KB

    const int tid  = threadIdx.x;
    const int lane = tid & 63;
    const int w    = tid >> 6;        // 0..7 = token octile (and staging role id)
    const int quad = lane >> 4;
    const int l15  = lane & 15;
    const int tb   = blockIdx.x >> 2; // token group (512 tokens)
    const int cq   = blockIdx.x & 3;  // code quarter
    const int t0   = tb * 512;
    const int cbase = cq * 2048;

    // staging: window m: chunk c2=(m>>2)&63 (codes cbase+c2*32+row), k-window
    // kw2=m&3. 4 loads x 1 KB, 8 rows x 128 B each, k-slot XOR-swizzled by
    // row for conflict-free ds_read_b128 (layout byte-identical to R1/R6).
    const int srow = lane >> 3;       // 0..7
    const int ssl  = lane & 7;        // LDS slot position
    // addr(chunk C, kw KW, octet q) = pstage + C*8192 + q*2048 + KW*64
    //   == (cbase + C*32 + q*8 + srow)*DIM + KW*64 + (ssl^srow)*8
    const unsigned short* pstage = cbb + (size_t)(cbase + srow) * DIM + (ssl ^ srow) * 8;

    #define STAGEW(PC, KW)                                                              \
        {                                                                               \
            _Pragma("unroll")                                                           \
            for (int q = 0; q < 4; ++q) {                                               \
                __builtin_amdgcn_global_load_lds(                                       \
                    (const __attribute__((address_space(1))) void*)((PC) + (KW) * 64 + q * 2048), \
                    (__attribute__((address_space(3))) void*)(&cs[(KW) * 2048 + q * 512]), \
                    16, 0, 0);                                                          \
            }                                                                           \
        }

    // 4 hoisted per-lane LDS fragment pointers (kk,j); buffer select BP is a
    // compile-time +BP*2048 elements -> folds into ds_read offset immediate.
    const unsigned short* fragp[4];
    #pragma unroll
    for (int kk = 0; kk < 2; ++kk)
        #pragma unroll
        for (int j = 0; j < 2; ++j) {
            int row = j * 16 + l15;
            int sl = (kk * 4 + quad) ^ (l15 & 7);
            fragp[kk * 2 + j] = &cs[row * 64 + sl * 8];
        }

    #define READFRAGS(FB, BP)                                                           \
        {                                                                               \
            _Pragma("unroll")                                                           \
            for (int f = 0; f < 4; ++f)                                                 \
                (FB)[f] = *(const s16x8*)(fragp[f] + (BP) * 2048);                      \
        }

    // prologue: w2 -> LDS; windows 0..3 staged by waves 0..3 (window m is
    // always staged by wave m&7); build A from fp32 z_e
    ((float4*)w2s)[tid] = ((const float4*)(w2g + cbase))[tid];
    if (w < 4) STAGEW(pstage, w);
    s16x8 af[4][8];
    #pragma unroll
    for (int i = 0; i < 4; ++i) {
        #pragma unroll
        for (int ks = 0; ks < 8; ++ks) {
            const float* p = z_e + (size_t)(t0 + w * 64 + i * 16 + l15) * DIM + ks * 32 + quad * 8;
            float4 a = *(const float4*)p;
            float4 b = *(const float4*)(p + 4);
            s16x8 v;
            v[0] = (short)f2bf(a.x); v[1] = (short)f2bf(a.y);
            v[2] = (short)f2bf(a.z); v[3] = (short)f2bf(a.w);
            v[4] = (short)f2bf(b.x); v[5] = (short)f2bf(b.y);
            v[6] = (short)f2bf(b.z); v[7] = (short)f2bf(b.w);
            af[i][ks] = v;
        }
    }

    float best[4][4];
    int   bidx[4][4];
    #pragma unroll
    for (int i = 0; i < 4; ++i)
        #pragma unroll
        for (int r = 0; r < 4; ++r) { best[i][r] = FLT_MAX; bidx[i][r] = 0x7FFFFFFF; }

    // prime: drain ALL prologue VMEM, publish w2s + windows 0..3; read window
    // 0; retire those reads everywhere before phase 0's restage of buf[0].
    s16x8 regB[2][4];
    __builtin_amdgcn_s_waitcnt(0x0F70);   // vmcnt(0)
    __syncthreads();
    READFRAGS(regB[0], 0);
    __builtin_amdgcn_s_waitcnt(0xC07F);   // lgkmcnt(0)
    __builtin_amdgcn_s_barrier();

    for (int c = 0; c < 64; ++c) {
        const int sb = (c & 1) ? 0 : 4;   // stager id base: (p+4)&7 = sb+kw
        const int db = (c & 1) ? 6 : 2;   // drainer id base: (p+2)&7 = (db+kw)&7
        const unsigned short* pcn = pstage + ((size_t)((c + 1) & 63) << 13);

        f32x4 acc[4][2];
        #pragma unroll
        for (int i = 0; i < 4; ++i)
            #pragma unroll
            for (int j = 0; j < 2; ++j) acc[i][j] = (f32x4){0.f, 0.f, 0.f, 0.f};

        #pragma unroll
        for (int kw = 0; kw < 4; ++kw) {
            // p = c*4 + kw;  window p+4 = chunk (c+1)&63, k-window kw, buf kw
            if (w == sb + kw) STAGEW(pcn, kw);
            if (w == ((db + kw) & 7)) __builtin_amdgcn_s_waitcnt(0x0F70);  // vmcnt(0)
            READFRAGS(regB[(kw + 1) & 1], (kw + 1) & 3);
            const s16x8* cur = regB[kw & 1];
            __builtin_amdgcn_s_setprio(1);
            #pragma unroll
            for (int kk = 0; kk < 2; ++kk)
                #pragma unroll
                for (int i = 0; i < 4; ++i)
                    #pragma unroll
                    for (int j = 0; j < 2; ++j)
                        acc[i][j] = __builtin_amdgcn_mfma_f32_16x16x32_bf16(af[i][kw * 2 + kk], cur[kk * 2 + j], acc[i][j], 0, 0, 0);
            __builtin_amdgcn_s_setprio(0);
            __builtin_amdgcn_s_waitcnt(0xC07F);   // lgkmcnt(0): my frag reads retired
            __builtin_amdgcn_s_barrier();          // publish window p+2; release buf[(p+1)&3]
        }

        // fold chunk c into running argmin: score = w2[col] - 2*dot
        #pragma unroll
        for (int j = 0; j < 2; ++j) {
            int col = cbase + c * 32 + j * 16 + l15;
            float w2v = w2s[c * 32 + j * 16 + l15];
            #pragma unroll
            for (int i = 0; i < 4; ++i)
                #pragma unroll
                for (int r = 0; r < 4; ++r) {
                    float s = fmaf(-2.0f, acc[i][j][r], w2v);
                    if (s < best[i][r]) { best[i][r] = s; bidx[i][r] = col; }  // ascending col: < keeps lowest
                }
        }
    }

    // cross-lane argmin over the 16 cols held per token row, then global
    // atomicMin merge across the 4 code-quarter blocks (monotonic u64 key)
    #pragma unroll
    for (int i = 0; i < 4; ++i)
        #pragma unroll
        for (int r = 0; r < 4; ++r) {
            float b = best[i][r]; int ix = bidx[i][r];
            #pragma unroll
            for (int m = 1; m < 16; m <<= 1) {
                float ob = __shfl_xor(b, m);
                int   oi = __shfl_xor(ix, m);
                if (ob < b || (ob == b && oi < ix)) { b = ob; ix = oi; }
            }
            if (l15 == 0) {
                unsigned int fb = __float_as_uint(b);
                fb = (fb & 0x80000000u) ? ~fb : (fb | 0x80000000u);   // monotonic key
                unsigned long long key = ((unsigned long long)fb << 32) | (unsigned int)ix;
                int tok = t0 + w * 64 + i * 16 + quad * 4 + r;
                atomicMin((unsigned long long*)(out + ((size_t)tok << 8)), key);
            }
        }
}

// ---------------------------------------------------------------------------
// gather: keys from out's z_q slots (lane-parallel fetch), gather codebook
// rows (overwriting keys), fused loss + plain flag store. 64 tokens/block.
__global__ __launch_bounds__(256) void vq_gather(const float* __restrict__ cb,
                                                 const float* __restrict__ z_e,
                                                 float* __restrict__ out,
                                                 int* __restrict__ flags) {
    __shared__ float wls[4];
    const int tid  = threadIdx.x;
    const int lane = tid & 63;
    const int w    = tid >> 6;        // 0..3; wave owns 16 tokens
    const int tw   = blockIdx.x * 64 + w * 16;

    // lanes 0..15 fetch the 16 keys in parallel; broadcast via shfl
    int myk = 0;
    if (lane < 16)
        myk = (int)(unsigned int)(*(const unsigned long long*)(out + ((size_t)(tw + lane) << 8)) & 0xFFFFFFFFull);

    float lsum = 0.0f;
    #pragma unroll 4
    for (int i = 0; i < 16; ++i) {
        int tok = tw + i;
        int k = __shfl(myk, i);
        if (lane == 0) flags[k] = 1;   // benign race
        float4 cv = *(const float4*)(cb + (size_t)k * DIM + lane * 4);
        float4 zv = *(const float4*)(z_e + (size_t)tok * DIM + lane * 4);
        float dx = zv.x - cv.x, dy = zv.y - cv.y, dz = zv.z - cv.z, dw = zv.w - cv.w;
        lsum += dx * dx + dy * dy + dz * dz + dw * dw;
        *(float4*)(out + ((size_t)tok << 8) + lane * 4) = cv;
    }
    #pragma unroll
    for (int m = 32; m >= 1; m >>= 1) lsum += __shfl_xor(lsum, m);
    if (lane == 0) wls[w] = lsum;
    __syncthreads();
    if (tid == 0) {
        float bsum = wls[0] + wls[1] + wls[2] + wls[3];
        // loss = codebook + 0.25*commitment = 1.25 * mean(diff^2)
        atomicAdd(out + LOSS_IDX, bsum * (1.25f / (float)LOSS_IDX));
    }
}

// ---------------------------------------------------------------------------
__global__ __launch_bounds__(256) void vq_usage(const int* __restrict__ flags,
                                                float* __restrict__ out) {
    __shared__ int ws[4];
    int tid = threadIdx.x;
    int s = 0;
    for (int i = tid; i < KC; i += 256) s += flags[i];
    #pragma unroll
    for (int m = 32; m >= 1; m >>= 1) s += __shfl_xor(s, m);
    if ((tid & 63) == 0) ws[tid >> 6] = s;
    __syncthreads();
    if (tid == 0) out[USAGE_IDX] = (float)(ws[0] + ws[1] + ws[2] + ws[3]) / (float)KC;
}

// ---------------------------------------------------------------------------
extern "C" void kernel_launch(void* const* d_in, const int* in_sizes, int n_in,
                              void* d_out, int out_size, void* d_ws, size_t ws_size,
                              hipStream_t stream) {
    (void)in_sizes; (void)n_in; (void)out_size; (void)ws_size;
    const float* z_e = (const float*)d_in[0];
    const float* cb  = (const float*)d_in[1];
    float* out = (float*)d_out;

    char* ws = (char*)d_ws;
    float* w2    = (float*)(ws + WS_W2);
    int*   flags = (int*)(ws + WS_FLAGS);
    unsigned short* cbb = (unsigned short*)(ws + WS_CBF);

    vq_prep<<<KC / 8, 256, 0, stream>>>(cb, cbb, w2, flags, out);
    vq_main<<<256, 512, 0, stream>>>(cbb, w2, z_e, out);
    vq_gather<<<T_TOTAL / 64, 256, 0, stream>>>(cb, z_e, out, flags);
    vq_usage<<<1, 256, 0, stream>>>(flags, out);
}